// Round 1
// baseline (477.514 us; speedup 1.0000x reference)
//
#include <hip/hip_runtime.h>
#include <math.h>

// VQ quantizer: z [N,64] fp32, codebook [512,64] fp32.
// out layout (all fp32): q_ste [N*64] | loss [1] | ids-as-float [N]
//
// Numerics contract: distances must replicate the reference fp32 rounding:
//   d2 = (z2 - 2*dot) + c2   (2*dot exact, so fmaf(-2,dot,z2) is identical)
// argmin with strict '<' over ascending k = first-index tie-break (numpy).

constexpr int D   = 64;
constexpr int D4  = 16;     // floats4 per row
constexpr int K   = 512;
constexpr int TILE_K = 128; // codewords per LDS tile (32 KB)
constexpr int BLOCK  = 256;
constexpr int ROWS_PER_BLOCK = 2 * BLOCK; // 2 rows per thread

#define FMA4(acc, zz, cc) do { \
  acc = fmaf((zz).x, (cc).x, acc); \
  acc = fmaf((zz).y, (cc).y, acc); \
  acc = fmaf((zz).z, (cc).z, acc); \
  acc = fmaf((zz).w, (cc).w, acc); } while (0)

__global__ __launch_bounds__(BLOCK)
void vq_main(const float* __restrict__ z, const float* __restrict__ cbk,
             float* __restrict__ out, float* __restrict__ lossAcc, int N)
{
    __shared__ float4 cb_tile[TILE_K * D4]; // 32 KB
    __shared__ float  c2s[K];               // 2 KB
    __shared__ float  wsum[BLOCK / 64];

    const int tid = threadIdx.x;
    const long rowBase = (long)blockIdx.x * ROWS_PER_BLOCK;
    const long r0 = rowBase + tid;
    const long r1 = rowBase + tid + BLOCK;

    // Codeword squared norms (fp32 sequential fma; error ~1e-8, far below the
    // 7.6e-6 rounding grid of (z2-2dot)+c2 -> negligible argmin risk).
    for (int k = tid; k < K; k += BLOCK) {
        const float4* c4 = (const float4*)(cbk + (long)k * D);
        float s = 0.f;
        #pragma unroll
        for (int i = 0; i < D4; ++i) { float4 c = c4[i]; FMA4(s, c, c); }
        c2s[k] = s;
    }

    // z rows into registers (128 VGPRs) + row norms.
    float4 z0[D4], z1[D4];
    {
        const float4* zp0 = (const float4*)(z + r0 * D);
        const float4* zp1 = (const float4*)(z + r1 * D);
        #pragma unroll
        for (int i = 0; i < D4; ++i) { z0[i] = zp0[i]; z1[i] = zp1[i]; }
    }
    float z2_0 = 0.f, z2_1 = 0.f;
    #pragma unroll
    for (int i = 0; i < D4; ++i) { FMA4(z2_0, z0[i], z0[i]); }
    #pragma unroll
    for (int i = 0; i < D4; ++i) { FMA4(z2_1, z1[i], z1[i]); }

    float best0 = INFINITY, best1 = INFINITY;
    int   bi0 = 0, bi1 = 0;

    for (int t = 0; t < K; t += TILE_K) {
        __syncthreads(); // protect previous tile readers (and c2s on t=0)
        const float4* src = (const float4*)(cbk + (long)t * D);
        for (int i = tid; i < TILE_K * D4; i += BLOCK) cb_tile[i] = src[i];
        __syncthreads();

        for (int k = 0; k < TILE_K; ++k) {
            const float4* crow = cb_tile + k * D4;
            // 4 independent FMA chains (2 per row) for ILP; combine once.
            float a0 = 0.f, b0 = 0.f, a1 = 0.f, b1 = 0.f;
            #pragma unroll
            for (int i = 0; i < D4; i += 2) {
                float4 ca = crow[i];
                float4 cb2 = crow[i + 1];
                FMA4(a0, z0[i],     ca);
                FMA4(b0, z0[i + 1], cb2);
                FMA4(a1, z1[i],     ca);
                FMA4(b1, z1[i + 1], cb2);
            }
            float dot0 = a0 + b0;
            float dot1 = a1 + b1;
            float c2 = c2s[t + k];
            float d0 = fmaf(-2.f, dot0, z2_0) + c2;
            float d1 = fmaf(-2.f, dot1, z2_1) + c2;
            int kg = t + k;
            if (d0 < best0) { best0 = d0; bi0 = kg; }
            if (d1 < best1) { best1 = d1; bi1 = kg; }
        }
    }

    // Epilogue: gather q (codebook is L2-hot), write q_ste = z + (q - z),
    // accumulate loss contribution sum((z-q)^2) == sum(u*u), u = q - z.
    float lacc = 0.f;
    {
        const float4* qp = (const float4*)(cbk + (long)bi0 * D);
        float4* o = (float4*)(out + r0 * D);
        #pragma unroll
        for (int i = 0; i < D4; ++i) {
            float4 q = qp[i], zz = z0[i], u, qs;
            u.x = q.x - zz.x; u.y = q.y - zz.y; u.z = q.z - zz.z; u.w = q.w - zz.w;
            qs.x = zz.x + u.x; qs.y = zz.y + u.y; qs.z = zz.z + u.z; qs.w = zz.w + u.w;
            FMA4(lacc, u, u);
            o[i] = qs;
        }
    }
    {
        const float4* qp = (const float4*)(cbk + (long)bi1 * D);
        float4* o = (float4*)(out + r1 * D);
        #pragma unroll
        for (int i = 0; i < D4; ++i) {
            float4 q = qp[i], zz = z1[i], u, qs;
            u.x = q.x - zz.x; u.y = q.y - zz.y; u.z = q.z - zz.z; u.w = q.w - zz.w;
            qs.x = zz.x + u.x; qs.y = zz.y + u.y; qs.z = zz.z + u.z; qs.w = zz.w + u.w;
            FMA4(lacc, u, u);
            o[i] = qs;
        }
    }

    float* idsOut = out + (long)N * D + 1;
    idsOut[r0] = (float)bi0;
    idsOut[r1] = (float)bi1;

    // Loss: wave shuffle reduce -> per-wave LDS -> one atomicAdd per block.
    #pragma unroll
    for (int off = 32; off > 0; off >>= 1) lacc += __shfl_down(lacc, off, 64);
    if ((tid & 63) == 0) wsum[tid >> 6] = lacc;
    __syncthreads();
    if (tid == 0) {
        float s = wsum[0] + wsum[1] + wsum[2] + wsum[3];
        atomicAdd(lossAcc, s);
    }
}

__global__ void vq_finalize(float* __restrict__ out,
                            const float* __restrict__ lossAcc, int N)
{
    out[(long)N * D] = 1.25f * (lossAcc[0] / (float)((long)N * D));
}

extern "C" void kernel_launch(void* const* d_in, const int* in_sizes, int n_in,
                              void* d_out, int out_size, void* d_ws, size_t ws_size,
                              hipStream_t stream)
{
    const float* z   = (const float*)d_in[0];
    const float* cbk = (const float*)d_in[1];
    float* out = (float*)d_out;
    float* ws  = (float*)d_ws;
    const int N = in_sizes[0] / D;

    hipMemsetAsync(ws, 0, sizeof(float), stream);
    const int blocks = N / ROWS_PER_BLOCK;
    vq_main<<<blocks, BLOCK, 0, stream>>>(z, cbk, out, ws, N);
    vq_finalize<<<1, 1, 0, stream>>>(out, ws, N);
}